// Round 1
// baseline (820.389 us; speedup 1.0000x reference)
//
#include <hip/hip_runtime.h>

#define NUM_USERS 60000
#define NUM_ITEMS 40000
#define NUM_NODES 100000
#define DIM       64
#define NUM_EDGES 1200000
#define BATCH     16384

// ---------------------------------------------------------------------------
// concat user_emb / item_emb into x (float4-vectorized; both segments are
// multiples of 16 float4s so the boundary is float4-aligned)
// ---------------------------------------------------------------------------
__global__ __launch_bounds__(256) void concat_kernel(
    const float4* __restrict__ ue, const float4* __restrict__ ie,
    float4* __restrict__ x)
{
    const int nU4 = NUM_USERS * (DIM / 4);       // 960000
    const int total4 = NUM_NODES * (DIM / 4);    // 1600000
    int i = blockIdx.x * blockDim.x + threadIdx.x;
    int stride = gridDim.x * blockDim.x;
    for (; i < total4; i += stride) {
        x[i] = (i < nU4) ? ue[i] : ie[i - nU4];
    }
}

// ---------------------------------------------------------------------------
// SpMM scatter: one 64-lane wave per edge, lane = embedding dim.
//   y[row*64 + lane] += val * x[col*64 + lane]
// Gather and atomic are both 64x4B = 256B coalesced per wave.
// ---------------------------------------------------------------------------
__global__ __launch_bounds__(256) void spmm_scatter(
    const int*   __restrict__ rows,
    const int*   __restrict__ cols,
    const float* __restrict__ vals,
    const float* __restrict__ x,
    float*       __restrict__ y)
{
    int wid  = (blockIdx.x * blockDim.x + threadIdx.x) >> 6;  // edge id
    int lane = threadIdx.x & 63;
    if (wid >= NUM_EDGES) return;
    int   r = rows[wid];
    int   c = cols[wid];
    float v = vals[wid];
    float xi = x[c * DIM + lane];
    atomicAdd(&y[r * DIM + lane], v * xi);
}

// ---------------------------------------------------------------------------
// Batched dot: one wave per batch element; 6-step shuffle reduction.
// ---------------------------------------------------------------------------
__global__ __launch_bounds__(256) void dot_kernel(
    const int*   __restrict__ uidx,
    const int*   __restrict__ iidx,
    const float* __restrict__ x,
    float*       __restrict__ out)
{
    int wid  = (blockIdx.x * blockDim.x + threadIdx.x) >> 6;  // batch id
    int lane = threadIdx.x & 63;
    if (wid >= BATCH) return;
    int u = uidx[wid];
    int it = iidx[wid];
    float a = x[u * DIM + lane];
    float b = x[(NUM_USERS + it) * DIM + lane];
    float p = a * b;
    #pragma unroll
    for (int off = 32; off > 0; off >>= 1)
        p += __shfl_down(p, off);
    if (lane == 0) out[wid] = p;
}

extern "C" void kernel_launch(void* const* d_in, const int* in_sizes, int n_in,
                              void* d_out, int out_size, void* d_ws, size_t ws_size,
                              hipStream_t stream)
{
    const int*   user_indices = (const int*)  d_in[0];
    const int*   item_indices = (const int*)  d_in[1];
    const int*   edge_rows    = (const int*)  d_in[2];
    const int*   edge_cols    = (const int*)  d_in[3];
    const float* edge_vals    = (const float*)d_in[4];
    const float* user_emb     = (const float*)d_in[5];
    const float* item_emb     = (const float*)d_in[6];
    float*       out          = (float*)      d_out;

    const size_t nfloats = (size_t)NUM_NODES * DIM;  // 6.4M floats, 25.6 MB
    float* bufA = (float*)d_ws;
    float* bufB = bufA + nfloats;

    // x0 = concat(user_emb, item_emb)
    concat_kernel<<<2048, 256, 0, stream>>>(
        (const float4*)user_emb, (const float4*)item_emb, (float4*)bufA);

    const float* x = bufA;
    float*       y = bufB;
    const int scatter_grid = (NUM_EDGES * 64) / 256;  // 300000 blocks, exact
    for (int layer = 0; layer < 3; ++layer) {
        hipMemsetAsync(y, 0, nfloats * sizeof(float), stream);
        spmm_scatter<<<scatter_grid, 256, 0, stream>>>(
            edge_rows, edge_cols, edge_vals, x, y);
        // ping-pong
        float* t = (float*)x;
        x = y;
        y = t;
    }

    dot_kernel<<<(BATCH * 64) / 256, 256, 0, stream>>>(
        user_indices, item_indices, x, out);
}

// Round 2
// 386.026 us; speedup vs baseline: 2.1252x; 2.1252x over previous
//
#include <hip/hip_runtime.h>

#define NUM_USERS 60000
#define NUM_ITEMS 40000
#define NUM_NODES 100000
#define DIM       64
#define NUM_EDGES 1200000
#define BATCH     16384

// ---------------------------------------------------------------------------
// 1) degree histogram: deg[row]++ for each edge (int atomics, L2-resident)
// ---------------------------------------------------------------------------
__global__ __launch_bounds__(256) void hist_kernel(
    const int* __restrict__ rows, int* __restrict__ deg)
{
    int i = blockIdx.x * blockDim.x + threadIdx.x;
    if (i < NUM_EDGES) atomicAdd(&deg[rows[i]], 1);
}

// ---------------------------------------------------------------------------
// 2a) per-block exclusive scan over 1024 elements (256 thr x 4), emit block sum
// ---------------------------------------------------------------------------
__global__ __launch_bounds__(256) void scan_blocks(
    const int* __restrict__ deg, int* __restrict__ excl, int* __restrict__ bsums)
{
    __shared__ int sdata[256];
    int t = threadIdx.x;
    int base = blockIdx.x * 1024 + t * 4;
    int v[4], ex[4];
    int run = 0;
    #pragma unroll
    for (int j = 0; j < 4; ++j) {
        int idx = base + j;
        v[j] = (idx < NUM_NODES) ? deg[idx] : 0;
        ex[j] = run;
        run += v[j];
    }
    sdata[t] = run;
    __syncthreads();
    // inclusive Hillis-Steele over 256 thread totals
    #pragma unroll
    for (int off = 1; off < 256; off <<= 1) {
        int x = (t >= off) ? sdata[t - off] : 0;
        __syncthreads();
        sdata[t] += x;
        __syncthreads();
    }
    int texcl = (t == 0) ? 0 : sdata[t - 1];
    #pragma unroll
    for (int j = 0; j < 4; ++j) {
        int idx = base + j;
        if (idx < NUM_NODES) excl[idx] = texcl + ex[j];
    }
    if (t == 255) bsums[blockIdx.x] = sdata[255];
}

// ---------------------------------------------------------------------------
// 2b) single-block exclusive scan of block sums (nb <= 256)
// ---------------------------------------------------------------------------
__global__ __launch_bounds__(256) void scan_sums(int* __restrict__ bsums, int nb)
{
    __shared__ int s[256];
    int t = threadIdx.x;
    s[t] = (t < nb) ? bsums[t] : 0;
    __syncthreads();
    #pragma unroll
    for (int off = 1; off < 256; off <<= 1) {
        int x = (t >= off) ? s[t - off] : 0;
        __syncthreads();
        s[t] += x;
        __syncthreads();
    }
    if (t < nb) bsums[t] = (t == 0) ? 0 : s[t - 1];
}

// ---------------------------------------------------------------------------
// 2c) add block offsets -> rowptr; also init cursor = rowptr
// ---------------------------------------------------------------------------
__global__ __launch_bounds__(256) void add_offsets(
    int* __restrict__ excl, const int* __restrict__ bsums, int* __restrict__ cursor)
{
    int i = blockIdx.x * blockDim.x + threadIdx.x;
    if (i < NUM_NODES) {
        int p = excl[i] + bsums[i >> 10];
        excl[i] = p;
        cursor[i] = p;
    }
}

// ---------------------------------------------------------------------------
// 3) scatter edges into CSR order, packing (col, val) into int2
// ---------------------------------------------------------------------------
__global__ __launch_bounds__(256) void scatter_edges(
    const int* __restrict__ rows, const int* __restrict__ cols,
    const float* __restrict__ vals, int* __restrict__ cursor,
    int2* __restrict__ csr)
{
    int i = blockIdx.x * blockDim.x + threadIdx.x;
    if (i >= NUM_EDGES) return;
    int r = rows[i];
    int pos = atomicAdd(&cursor[r], 1);
    csr[pos] = make_int2(cols[i], __float_as_int(vals[i]));
}

// ---------------------------------------------------------------------------
// 4) CSR SpMM: one 64-lane wave per row, lane = dim. No atomics, one store.
//    Layer-1 reads directly from (user_emb, item_emb); later layers pass
//    xu = x, xi = x + NUM_USERS*DIM so both branches resolve to x.
// ---------------------------------------------------------------------------
__global__ __launch_bounds__(256) void spmm_csr(
    const int*  __restrict__ rowptr, const int* __restrict__ deg,
    const int2* __restrict__ csr,
    const float* __restrict__ xu, const float* __restrict__ xi,
    float* __restrict__ y)
{
    int wid  = (blockIdx.x * blockDim.x + threadIdx.x) >> 6;  // row
    int lane = threadIdx.x & 63;
    if (wid >= NUM_NODES) return;
    int start = rowptr[wid];
    int end   = start + deg[wid];
    float acc = 0.f;
    int e = start;
    for (; e + 1 < end; e += 2) {
        int2 p0 = csr[e];
        int2 p1 = csr[e + 1];
        int c0 = p0.x, c1 = p1.x;
        const float* s0 = (c0 < NUM_USERS) ? xu + (size_t)c0 * DIM
                                           : xi + (size_t)(c0 - NUM_USERS) * DIM;
        const float* s1 = (c1 < NUM_USERS) ? xu + (size_t)c1 * DIM
                                           : xi + (size_t)(c1 - NUM_USERS) * DIM;
        float a0 = s0[lane];
        float a1 = s1[lane];
        acc = fmaf(__int_as_float(p0.y), a0, acc);
        acc = fmaf(__int_as_float(p1.y), a1, acc);
    }
    if (e < end) {
        int2 p0 = csr[e];
        int c0 = p0.x;
        const float* s0 = (c0 < NUM_USERS) ? xu + (size_t)c0 * DIM
                                           : xi + (size_t)(c0 - NUM_USERS) * DIM;
        acc = fmaf(__int_as_float(p0.y), s0[lane], acc);
    }
    y[(size_t)wid * DIM + lane] = acc;
}

// ---------------------------------------------------------------------------
// 5) batched dot: one wave per batch element
// ---------------------------------------------------------------------------
__global__ __launch_bounds__(256) void dot_kernel(
    const int*   __restrict__ uidx,
    const int*   __restrict__ iidx,
    const float* __restrict__ x,
    float*       __restrict__ out)
{
    int wid  = (blockIdx.x * blockDim.x + threadIdx.x) >> 6;
    int lane = threadIdx.x & 63;
    if (wid >= BATCH) return;
    int u  = uidx[wid];
    int it = iidx[wid];
    float a = x[(size_t)u * DIM + lane];
    float b = x[((size_t)NUM_USERS + it) * DIM + lane];
    float p = a * b;
    #pragma unroll
    for (int off = 32; off > 0; off >>= 1)
        p += __shfl_down(p, off);
    if (lane == 0) out[wid] = p;
}

extern "C" void kernel_launch(void* const* d_in, const int* in_sizes, int n_in,
                              void* d_out, int out_size, void* d_ws, size_t ws_size,
                              hipStream_t stream)
{
    const int*   user_indices = (const int*)  d_in[0];
    const int*   item_indices = (const int*)  d_in[1];
    const int*   edge_rows    = (const int*)  d_in[2];
    const int*   edge_cols    = (const int*)  d_in[3];
    const float* edge_vals    = (const float*)d_in[4];
    const float* user_emb     = (const float*)d_in[5];
    const float* item_emb     = (const float*)d_in[6];
    float*       out          = (float*)      d_out;

    // ---- workspace layout (all 256B-aligned) ----
    const size_t nfloats = (size_t)NUM_NODES * DIM;       // 6.4M
    char* p = (char*)d_ws;
    float* bufA   = (float*)p;            p += nfloats * 4;          // 25.6 MB
    float* bufB   = (float*)p;            p += nfloats * 4;          // 25.6 MB
    int*   deg    = (int*)p;              p += 102400 * 4;           // 0.4 MB
    int*   rowptr = (int*)p;              p += 102400 * 4;           // 0.4 MB
    int*   cursor = (int*)p;              p += 102400 * 4;           // 0.4 MB
    int*   bsums  = (int*)p;              p += 256 * 4;
    int2*  csr    = (int2*)p;             p += (size_t)NUM_EDGES * 8; // 9.6 MB

    const int NB_EDGE = (NUM_EDGES + 255) / 256;    // 4688
    const int NB_SCAN = (NUM_NODES + 1023) / 1024;  // 98
    const int NB_NODE = (NUM_NODES + 255) / 256;    // 391

    // ---- build CSR ----
    hipMemsetAsync(deg, 0, NUM_NODES * sizeof(int), stream);
    hist_kernel<<<NB_EDGE, 256, 0, stream>>>(edge_rows, deg);
    scan_blocks<<<NB_SCAN, 256, 0, stream>>>(deg, rowptr, bsums);
    scan_sums<<<1, 256, 0, stream>>>(bsums, NB_SCAN);
    add_offsets<<<NB_NODE, 256, 0, stream>>>(rowptr, bsums, cursor);
    scatter_edges<<<NB_EDGE, 256, 0, stream>>>(
        edge_rows, edge_cols, edge_vals, cursor, csr);

    // ---- 3 SpMM layers (no atomics, no memsets) ----
    const int NB_SPMM = (NUM_NODES * 64) / 256;  // 25000
    // layer 1: gather from original embeddings
    spmm_csr<<<NB_SPMM, 256, 0, stream>>>(rowptr, deg, csr, user_emb, item_emb, bufA);
    // layer 2
    spmm_csr<<<NB_SPMM, 256, 0, stream>>>(rowptr, deg, csr, bufA, bufA + (size_t)NUM_USERS * DIM, bufB);
    // layer 3
    spmm_csr<<<NB_SPMM, 256, 0, stream>>>(rowptr, deg, csr, bufB, bufB + (size_t)NUM_USERS * DIM, bufA);

    // ---- final dot ----
    dot_kernel<<<(BATCH * 64) / 256, 256, 0, stream>>>(
        user_indices, item_indices, bufA, out);
}

// Round 3
// 305.076 us; speedup vs baseline: 2.6891x; 1.2653x over previous
//
#include <hip/hip_runtime.h>

#define NUM_USERS 60000
#define NUM_ITEMS 40000
#define NUM_NODES 100000
#define DIM       64
#define NUM_EDGES 1200000
#define BATCH     16384

// ---------------------------------------------------------------------------
// 1) degree histogram
// ---------------------------------------------------------------------------
__global__ __launch_bounds__(256) void hist_kernel(
    const int* __restrict__ rows, int* __restrict__ deg)
{
    int i = blockIdx.x * blockDim.x + threadIdx.x;
    if (i < NUM_EDGES) atomicAdd(&deg[rows[i]], 1);
}

// ---------------------------------------------------------------------------
// 2a) per-block exclusive scan over 1024 elements (256 thr x 4), emit block sum
// ---------------------------------------------------------------------------
__global__ __launch_bounds__(256) void scan_blocks(
    const int* __restrict__ deg, int* __restrict__ excl, int* __restrict__ bsums)
{
    __shared__ int sdata[256];
    int t = threadIdx.x;
    int base = blockIdx.x * 1024 + t * 4;
    int v[4], ex[4];
    int run = 0;
    #pragma unroll
    for (int j = 0; j < 4; ++j) {
        int idx = base + j;
        v[j] = (idx < NUM_NODES) ? deg[idx] : 0;
        ex[j] = run;
        run += v[j];
    }
    sdata[t] = run;
    __syncthreads();
    #pragma unroll
    for (int off = 1; off < 256; off <<= 1) {
        int x = (t >= off) ? sdata[t - off] : 0;
        __syncthreads();
        sdata[t] += x;
        __syncthreads();
    }
    int texcl = (t == 0) ? 0 : sdata[t - 1];
    #pragma unroll
    for (int j = 0; j < 4; ++j) {
        int idx = base + j;
        if (idx < NUM_NODES) excl[idx] = texcl + ex[j];
    }
    if (t == 255) bsums[blockIdx.x] = sdata[255];
}

// ---------------------------------------------------------------------------
// 2b) single-block exclusive scan of block sums (nb <= 256)
// ---------------------------------------------------------------------------
__global__ __launch_bounds__(256) void scan_sums(int* __restrict__ bsums, int nb)
{
    __shared__ int s[256];
    int t = threadIdx.x;
    s[t] = (t < nb) ? bsums[t] : 0;
    __syncthreads();
    #pragma unroll
    for (int off = 1; off < 256; off <<= 1) {
        int x = (t >= off) ? s[t - off] : 0;
        __syncthreads();
        s[t] += x;
        __syncthreads();
    }
    if (t < nb) bsums[t] = (t == 0) ? 0 : s[t - 1];
}

// ---------------------------------------------------------------------------
// 2c) add block offsets -> rowptr; also init cursor = rowptr
// ---------------------------------------------------------------------------
__global__ __launch_bounds__(256) void add_offsets(
    int* __restrict__ excl, const int* __restrict__ bsums, int* __restrict__ cursor)
{
    int i = blockIdx.x * blockDim.x + threadIdx.x;
    if (i < NUM_NODES) {
        int p = excl[i] + bsums[i >> 10];
        excl[i] = p;
        cursor[i] = p;
    }
}

// ---------------------------------------------------------------------------
// 3) scatter edges into CSR order; packed 8B non-temporal store (no RFO fill)
// ---------------------------------------------------------------------------
__global__ __launch_bounds__(256) void scatter_edges(
    const int* __restrict__ rows, const int* __restrict__ cols,
    const float* __restrict__ vals, int* __restrict__ cursor,
    long long* __restrict__ csr)
{
    int i = blockIdx.x * blockDim.x + threadIdx.x;
    if (i >= NUM_EDGES) return;
    int r = rows[i];
    int pos = atomicAdd(&cursor[r], 1);
    long long packed = ((long long)(unsigned)__float_as_int(vals[i]) << 32)
                     | (unsigned)cols[i];
    __builtin_nontemporal_store(packed, csr + pos);
}

// ---------------------------------------------------------------------------
// 4) CSR SpMM: one wave per row; wave = 4 groups x 16 lanes; each group owns
//    an independent edge stream (stride 4), each lane holds float4 of dims.
//    Up to 8 gathers in flight per wave (2x inner unroll). No atomics.
// ---------------------------------------------------------------------------
__global__ __launch_bounds__(256) void spmm_csr(
    const int*  __restrict__ rowptr, const int* __restrict__ deg,
    const int2* __restrict__ csr,
    const float* __restrict__ xu, const float* __restrict__ xi,
    float* __restrict__ y)
{
    int wid  = (blockIdx.x * blockDim.x + threadIdx.x) >> 6;  // row
    int lane = threadIdx.x & 63;
    if (wid >= NUM_NODES) return;
    int g = lane >> 4;        // edge-slot group 0..3
    int q = lane & 15;        // float4 index within row (dims 4q..4q+3)
    int start = rowptr[wid];
    int end   = start + deg[wid];

    float4 acc = make_float4(0.f, 0.f, 0.f, 0.f);
    int e = start + g;
    // 2x unrolled: 2 independent gathers per group -> 8 per wave
    for (; e + 4 < end; e += 8) {
        int2 p0 = csr[e];
        int2 p1 = csr[e + 4];
        int c0 = p0.x, c1 = p1.x;
        const float4* s0 = (c0 < NUM_USERS)
            ? (const float4*)(xu + (size_t)c0 * DIM)
            : (const float4*)(xi + (size_t)(c0 - NUM_USERS) * DIM);
        const float4* s1 = (c1 < NUM_USERS)
            ? (const float4*)(xu + (size_t)c1 * DIM)
            : (const float4*)(xi + (size_t)(c1 - NUM_USERS) * DIM);
        float4 x0 = s0[q];
        float4 x1 = s1[q];
        float v0 = __int_as_float(p0.y);
        float v1 = __int_as_float(p1.y);
        acc.x = fmaf(v0, x0.x, acc.x); acc.y = fmaf(v0, x0.y, acc.y);
        acc.z = fmaf(v0, x0.z, acc.z); acc.w = fmaf(v0, x0.w, acc.w);
        acc.x = fmaf(v1, x1.x, acc.x); acc.y = fmaf(v1, x1.y, acc.y);
        acc.z = fmaf(v1, x1.z, acc.z); acc.w = fmaf(v1, x1.w, acc.w);
    }
    if (e < end) {
        int2 p0 = csr[e];
        int c0 = p0.x;
        const float4* s0 = (c0 < NUM_USERS)
            ? (const float4*)(xu + (size_t)c0 * DIM)
            : (const float4*)(xi + (size_t)(c0 - NUM_USERS) * DIM);
        float4 x0 = s0[q];
        float v0 = __int_as_float(p0.y);
        acc.x = fmaf(v0, x0.x, acc.x); acc.y = fmaf(v0, x0.y, acc.y);
        acc.z = fmaf(v0, x0.z, acc.z); acc.w = fmaf(v0, x0.w, acc.w);
    }

    // reduce the 4 groups' partials (lanes with equal q): xor over 16, 32
    #pragma unroll
    for (int off = 16; off < 64; off <<= 1) {
        acc.x += __shfl_xor(acc.x, off);
        acc.y += __shfl_xor(acc.y, off);
        acc.z += __shfl_xor(acc.z, off);
        acc.w += __shfl_xor(acc.w, off);
    }
    if (g == 0)
        ((float4*)(y + (size_t)wid * DIM))[q] = acc;
}

// ---------------------------------------------------------------------------
// 5) batched dot: one wave per batch element
// ---------------------------------------------------------------------------
__global__ __launch_bounds__(256) void dot_kernel(
    const int*   __restrict__ uidx,
    const int*   __restrict__ iidx,
    const float* __restrict__ x,
    float*       __restrict__ out)
{
    int wid  = (blockIdx.x * blockDim.x + threadIdx.x) >> 6;
    int lane = threadIdx.x & 63;
    if (wid >= BATCH) return;
    int u  = uidx[wid];
    int it = iidx[wid];
    float a = x[(size_t)u * DIM + lane];
    float b = x[((size_t)NUM_USERS + it) * DIM + lane];
    float p = a * b;
    #pragma unroll
    for (int off = 32; off > 0; off >>= 1)
        p += __shfl_down(p, off);
    if (lane == 0) out[wid] = p;
}

extern "C" void kernel_launch(void* const* d_in, const int* in_sizes, int n_in,
                              void* d_out, int out_size, void* d_ws, size_t ws_size,
                              hipStream_t stream)
{
    const int*   user_indices = (const int*)  d_in[0];
    const int*   item_indices = (const int*)  d_in[1];
    const int*   edge_rows    = (const int*)  d_in[2];
    const int*   edge_cols    = (const int*)  d_in[3];
    const float* edge_vals    = (const float*)d_in[4];
    const float* user_emb     = (const float*)d_in[5];
    const float* item_emb     = (const float*)d_in[6];
    float*       out          = (float*)      d_out;

    // ---- workspace layout ----
    const size_t nfloats = (size_t)NUM_NODES * DIM;       // 6.4M
    char* p = (char*)d_ws;
    float* bufA   = (float*)p;            p += nfloats * 4;          // 25.6 MB
    float* bufB   = (float*)p;            p += nfloats * 4;          // 25.6 MB
    int*   deg    = (int*)p;              p += 102400 * 4;
    int*   rowptr = (int*)p;              p += 102400 * 4;
    int*   cursor = (int*)p;              p += 102400 * 4;
    int*   bsums  = (int*)p;              p += 256 * 4;
    int2*  csr    = (int2*)p;             p += (size_t)NUM_EDGES * 8; // 9.6 MB

    const int NB_EDGE = (NUM_EDGES + 255) / 256;    // 4688
    const int NB_SCAN = (NUM_NODES + 1023) / 1024;  // 98
    const int NB_NODE = (NUM_NODES + 255) / 256;    // 391

    // ---- build CSR ----
    hipMemsetAsync(deg, 0, NUM_NODES * sizeof(int), stream);
    hist_kernel<<<NB_EDGE, 256, 0, stream>>>(edge_rows, deg);
    scan_blocks<<<NB_SCAN, 256, 0, stream>>>(deg, rowptr, bsums);
    scan_sums<<<1, 256, 0, stream>>>(bsums, NB_SCAN);
    add_offsets<<<NB_NODE, 256, 0, stream>>>(rowptr, bsums, cursor);
    scatter_edges<<<NB_EDGE, 256, 0, stream>>>(
        edge_rows, edge_cols, edge_vals, cursor, (long long*)csr);

    // ---- 3 SpMM layers ----
    const int NB_SPMM = (NUM_NODES * 64) / 256;  // 25000
    spmm_csr<<<NB_SPMM, 256, 0, stream>>>(rowptr, deg, csr, user_emb, item_emb, bufA);
    spmm_csr<<<NB_SPMM, 256, 0, stream>>>(rowptr, deg, csr, bufA, bufA + (size_t)NUM_USERS * DIM, bufB);
    spmm_csr<<<NB_SPMM, 256, 0, stream>>>(rowptr, deg, csr, bufB, bufB + (size_t)NUM_USERS * DIM, bufA);

    // ---- final dot ----
    dot_kernel<<<(BATCH * 64) / 256, 256, 0, stream>>>(
        user_indices, item_indices, bufA, out);
}

// Round 4
// 244.318 us; speedup vs baseline: 3.3579x; 1.2487x over previous
//
#include <hip/hip_runtime.h>

#define NUM_USERS 60000
#define NUM_ITEMS 40000
#define NUM_NODES 100000
#define DIM       64
#define NUM_EDGES 1200000
#define BATCH     16384

#define BROWS 256                 // rows per bucket
#define NBUCK 391                 // ceil(100000/256)
#define SORT_CAP 4096             // LDS staging capacity (mean 3072, +18 sigma)

// ---------------------------------------------------------------------------
// concat user_emb / item_emb into x (float4; segment boundary is f4-aligned)
// ---------------------------------------------------------------------------
__global__ __launch_bounds__(256) void concat_kernel(
    const float4* __restrict__ ue, const float4* __restrict__ ie,
    float4* __restrict__ x)
{
    const int nU4 = NUM_USERS * (DIM / 4);
    const int total4 = NUM_NODES * (DIM / 4);
    int i = blockIdx.x * blockDim.x + threadIdx.x;
    int stride = gridDim.x * blockDim.x;
    for (; i < total4; i += stride)
        x[i] = (i < nU4) ? ue[i] : ie[i - nU4];
}

// ---------------------------------------------------------------------------
// 1) degree histogram
// ---------------------------------------------------------------------------
__global__ __launch_bounds__(256) void hist_kernel(
    const int* __restrict__ rows, int* __restrict__ deg)
{
    int i = blockIdx.x * blockDim.x + threadIdx.x;
    if (i < NUM_EDGES) atomicAdd(&deg[rows[i]], 1);
}

// ---------------------------------------------------------------------------
// 2a) per-block exclusive scan over 1024 elements, emit block sum
// ---------------------------------------------------------------------------
__global__ __launch_bounds__(256) void scan_blocks(
    const int* __restrict__ deg, int* __restrict__ excl, int* __restrict__ bsums)
{
    __shared__ int sdata[256];
    int t = threadIdx.x;
    int base = blockIdx.x * 1024 + t * 4;
    int v[4], ex[4];
    int run = 0;
    #pragma unroll
    for (int j = 0; j < 4; ++j) {
        int idx = base + j;
        v[j] = (idx < NUM_NODES) ? deg[idx] : 0;
        ex[j] = run;
        run += v[j];
    }
    sdata[t] = run;
    __syncthreads();
    #pragma unroll
    for (int off = 1; off < 256; off <<= 1) {
        int x = (t >= off) ? sdata[t - off] : 0;
        __syncthreads();
        sdata[t] += x;
        __syncthreads();
    }
    int texcl = (t == 0) ? 0 : sdata[t - 1];
    #pragma unroll
    for (int j = 0; j < 4; ++j) {
        int idx = base + j;
        if (idx < NUM_NODES) excl[idx] = texcl + ex[j];
    }
    if (t == 255) bsums[blockIdx.x] = sdata[255];
}

// ---------------------------------------------------------------------------
// 2b) single-block exclusive scan of block sums (nb <= 256)
// ---------------------------------------------------------------------------
__global__ __launch_bounds__(256) void scan_sums(int* __restrict__ bsums, int nb)
{
    __shared__ int s[256];
    int t = threadIdx.x;
    s[t] = (t < nb) ? bsums[t] : 0;
    __syncthreads();
    #pragma unroll
    for (int off = 1; off < 256; off <<= 1) {
        int x = (t >= off) ? s[t - off] : 0;
        __syncthreads();
        s[t] += x;
        __syncthreads();
    }
    if (t < nb) bsums[t] = (t == 0) ? 0 : s[t - 1];
}

// ---------------------------------------------------------------------------
// 2c) add block offsets -> rowptr (+ sentinel rowptr[NUM_NODES] = NUM_EDGES)
// ---------------------------------------------------------------------------
__global__ __launch_bounds__(256) void add_offsets(
    int* __restrict__ excl, const int* __restrict__ bsums)
{
    int i = blockIdx.x * blockDim.x + threadIdx.x;
    if (i < NUM_NODES)
        excl[i] = excl[i] + bsums[i >> 10];
    else if (i == NUM_NODES)
        excl[i] = NUM_EDGES;
}

// ---------------------------------------------------------------------------
// 2d) bucket cursors: gcursor[b] = rowptr[b*BROWS]
// ---------------------------------------------------------------------------
__global__ __launch_bounds__(256) void init_cursors(
    const int* __restrict__ rowptr, int* __restrict__ gcursor)
{
    int b = blockIdx.x * blockDim.x + threadIdx.x;
    if (b < NBUCK) gcursor[b] = rowptr[b * BROWS];
}

// ---------------------------------------------------------------------------
// 3a) pass 1: bin edges into 391 coarse buckets. Each block reserves one
//     contiguous run per bucket -> writes get XCD-L2 temporal locality.
//     Packed u64: [val:32][lrow:8][col:17]
// ---------------------------------------------------------------------------
__global__ __launch_bounds__(256) void bin_edges(
    const int* __restrict__ rows, const int* __restrict__ cols,
    const float* __restrict__ vals, int* __restrict__ gcursor,
    unsigned long long* __restrict__ tmp)
{
    __shared__ int cnt[NBUCK], lcur[NBUCK], gbase[NBUCK];
    int t = threadIdx.x;
    for (int i = t; i < NBUCK; i += 256) { cnt[i] = 0; lcur[i] = 0; }
    __syncthreads();
    int base = blockIdx.x * 4096;
    int r[16], b[16];
    #pragma unroll
    for (int k = 0; k < 16; ++k) {
        int idx = base + k * 256 + t;
        if (idx < NUM_EDGES) {
            r[k] = rows[idx];
            b[k] = r[k] >> 8;
            atomicAdd(&cnt[b[k]], 1);
        } else b[k] = -1;
    }
    __syncthreads();
    for (int i = t; i < NBUCK; i += 256) {
        int c = cnt[i];
        gbase[i] = c ? atomicAdd(&gcursor[i], c) : 0;
    }
    __syncthreads();
    #pragma unroll
    for (int k = 0; k < 16; ++k) {
        int idx = base + k * 256 + t;
        if (idx < NUM_EDGES) {
            int col = cols[idx];
            unsigned vbits = (unsigned)__float_as_int(vals[idx]);
            int lofs = atomicAdd(&lcur[b[k]], 1);
            unsigned long long packed = ((unsigned long long)vbits << 32)
                | ((unsigned)(r[k] & 255) << 17) | (unsigned)col;
            tmp[(size_t)gbase[b[k]] + lofs] = packed;
        }
    }
}

// ---------------------------------------------------------------------------
// 3b) pass 2: one block per bucket; LDS counting sort to exact row order,
//     coalesced write-out. Fallback path for (impossible) overflow.
// ---------------------------------------------------------------------------
__global__ __launch_bounds__(256) void sort_buckets(
    const int* __restrict__ rowptr, const unsigned long long* __restrict__ tmp,
    int2* __restrict__ csr)
{
    __shared__ int rowcur[BROWS];
    __shared__ int2 stage[SORT_CAP];
    int b = blockIdx.x;
    int t = threadIdx.x;
    int first = b * BROWS;
    int rs = rowptr[first];
    int last = first + BROWS;
    if (last > NUM_NODES) last = NUM_NODES;
    int re = rowptr[last];
    int count = re - rs;
    int r = first + t;
    rowcur[t] = (r < NUM_NODES) ? rowptr[r] - rs : 0;
    __syncthreads();
    if (count <= SORT_CAP) {
        for (int i = t; i < count; i += 256) {
            unsigned long long v = tmp[(size_t)rs + i];
            int col  = (int)(v & 0x1FFFF);
            int lrow = (int)((v >> 17) & 0xFF);
            int pos  = atomicAdd(&rowcur[lrow], 1);
            stage[pos] = make_int2(col, (int)(v >> 32));
        }
        __syncthreads();
        for (int i = t; i < count; i += 256)
            csr[(size_t)rs + i] = stage[i];
    } else {
        for (int i = t; i < count; i += 256) {
            unsigned long long v = tmp[(size_t)rs + i];
            int col  = (int)(v & 0x1FFFF);
            int lrow = (int)((v >> 17) & 0xFF);
            int pos  = atomicAdd(&rowcur[lrow], 1);
            csr[(size_t)rs + pos] = make_int2(col, (int)(v >> 32));
        }
    }
}

// ---------------------------------------------------------------------------
// 4) CSR SpMM: 16 lanes per row (4 rows/wave), float4 per lane, 4x unroll
//    -> 16 independent 256B gathers in flight per wave, no shuffle reduce.
// ---------------------------------------------------------------------------
__global__ __launch_bounds__(256) void spmm_csr(
    const int*  __restrict__ rowptr, const int2* __restrict__ csr,
    const float* __restrict__ x, float* __restrict__ y)
{
    int tid = blockIdx.x * blockDim.x + threadIdx.x;
    int row = tid >> 4;
    if (row >= NUM_NODES) return;
    int q = tid & 15;
    int e   = rowptr[row];
    int end = rowptr[row + 1];
    const float4* xb = (const float4*)x;
    float4 acc = make_float4(0.f, 0.f, 0.f, 0.f);
    for (; e + 3 < end; e += 4) {
        int2 p0 = csr[e], p1 = csr[e + 1], p2 = csr[e + 2], p3 = csr[e + 3];
        float4 x0 = xb[((size_t)p0.x << 4) + q];
        float4 x1 = xb[((size_t)p1.x << 4) + q];
        float4 x2 = xb[((size_t)p2.x << 4) + q];
        float4 x3 = xb[((size_t)p3.x << 4) + q];
        float v0 = __int_as_float(p0.y), v1 = __int_as_float(p1.y);
        float v2 = __int_as_float(p2.y), v3 = __int_as_float(p3.y);
        acc.x = fmaf(v0, x0.x, acc.x); acc.y = fmaf(v0, x0.y, acc.y);
        acc.z = fmaf(v0, x0.z, acc.z); acc.w = fmaf(v0, x0.w, acc.w);
        acc.x = fmaf(v1, x1.x, acc.x); acc.y = fmaf(v1, x1.y, acc.y);
        acc.z = fmaf(v1, x1.z, acc.z); acc.w = fmaf(v1, x1.w, acc.w);
        acc.x = fmaf(v2, x2.x, acc.x); acc.y = fmaf(v2, x2.y, acc.y);
        acc.z = fmaf(v2, x2.z, acc.z); acc.w = fmaf(v2, x2.w, acc.w);
        acc.x = fmaf(v3, x3.x, acc.x); acc.y = fmaf(v3, x3.y, acc.y);
        acc.z = fmaf(v3, x3.z, acc.z); acc.w = fmaf(v3, x3.w, acc.w);
    }
    for (; e < end; ++e) {
        int2 p0 = csr[e];
        float4 x0 = xb[((size_t)p0.x << 4) + q];
        float v0 = __int_as_float(p0.y);
        acc.x = fmaf(v0, x0.x, acc.x); acc.y = fmaf(v0, x0.y, acc.y);
        acc.z = fmaf(v0, x0.z, acc.z); acc.w = fmaf(v0, x0.w, acc.w);
    }
    ((float4*)y)[((size_t)row << 4) + q] = acc;
}

// ---------------------------------------------------------------------------
// 5) batched dot: one wave per batch element
// ---------------------------------------------------------------------------
__global__ __launch_bounds__(256) void dot_kernel(
    const int*   __restrict__ uidx,
    const int*   __restrict__ iidx,
    const float* __restrict__ x,
    float*       __restrict__ out)
{
    int wid  = (blockIdx.x * blockDim.x + threadIdx.x) >> 6;
    int lane = threadIdx.x & 63;
    if (wid >= BATCH) return;
    int u  = uidx[wid];
    int it = iidx[wid];
    float a = x[(size_t)u * DIM + lane];
    float b = x[((size_t)NUM_USERS + it) * DIM + lane];
    float p = a * b;
    #pragma unroll
    for (int off = 32; off > 0; off >>= 1)
        p += __shfl_down(p, off);
    if (lane == 0) out[wid] = p;
}

extern "C" void kernel_launch(void* const* d_in, const int* in_sizes, int n_in,
                              void* d_out, int out_size, void* d_ws, size_t ws_size,
                              hipStream_t stream)
{
    const int*   user_indices = (const int*)  d_in[0];
    const int*   item_indices = (const int*)  d_in[1];
    const int*   edge_rows    = (const int*)  d_in[2];
    const int*   edge_cols    = (const int*)  d_in[3];
    const float* edge_vals    = (const float*)d_in[4];
    const float* user_emb     = (const float*)d_in[5];
    const float* item_emb     = (const float*)d_in[6];
    float*       out          = (float*)      d_out;

    // ---- workspace layout ----
    const size_t nfloats = (size_t)NUM_NODES * DIM;   // 6.4M floats
    char* p = (char*)d_ws;
    float* bufA    = (float*)p;   p += nfloats * 4;            // 25.6 MB (also tmp CSR, 9.6 MB)
    float* bufB    = (float*)p;   p += nfloats * 4;            // 25.6 MB
    int*   deg     = (int*)p;     p += 102400 * 4;
    int*   rowptr  = (int*)p;     p += 102400 * 4;             // +1 sentinel inside
    int*   gcursor = (int*)p;     p += 512 * 4;
    int*   bsums   = (int*)p;     p += 256 * 4;
    int2*  csr     = (int2*)p;    p += (size_t)NUM_EDGES * 8;  // 9.6 MB

    unsigned long long* tmp = (unsigned long long*)bufA;  // alias: dead before concat

    const int NB_EDGE = (NUM_EDGES + 255) / 256;        // 4688
    const int NB_SCAN = (NUM_NODES + 1023) / 1024;      // 98
    const int NB_NODE = (NUM_NODES + 256) / 256;        // 391 (covers sentinel)
    const int NB_BIN  = (NUM_EDGES + 4095) / 4096;      // 293

    // ---- build rowptr ----
    hipMemsetAsync(deg, 0, NUM_NODES * sizeof(int), stream);
    hist_kernel<<<NB_EDGE, 256, 0, stream>>>(edge_rows, deg);
    scan_blocks<<<NB_SCAN, 256, 0, stream>>>(deg, rowptr, bsums);
    scan_sums<<<1, 256, 0, stream>>>(bsums, NB_SCAN);
    add_offsets<<<NB_NODE, 256, 0, stream>>>(rowptr, bsums);
    init_cursors<<<2, 256, 0, stream>>>(rowptr, gcursor);

    // ---- two-pass bucket sort into exact CSR ----
    bin_edges<<<NB_BIN, 256, 0, stream>>>(edge_rows, edge_cols, edge_vals, gcursor, tmp);
    sort_buckets<<<NBUCK, 256, 0, stream>>>(rowptr, tmp, csr);

    // ---- concat embeddings (after tmp is dead) ----
    concat_kernel<<<2048, 256, 0, stream>>>(
        (const float4*)user_emb, (const float4*)item_emb, (float4*)bufA);

    // ---- 3 SpMM layers ----
    const int NB_SPMM = (NUM_NODES * 16 + 255) / 256;   // 6250
    spmm_csr<<<NB_SPMM, 256, 0, stream>>>(rowptr, csr, bufA, bufB);
    spmm_csr<<<NB_SPMM, 256, 0, stream>>>(rowptr, csr, bufB, bufA);
    spmm_csr<<<NB_SPMM, 256, 0, stream>>>(rowptr, csr, bufA, bufB);

    // ---- final dot ----
    dot_kernel<<<(BATCH * 64) / 256, 256, 0, stream>>>(
        user_indices, item_indices, bufB, out);
}

// Round 5
// 220.390 us; speedup vs baseline: 3.7224x; 1.1086x over previous
//
#include <hip/hip_runtime.h>

#define NUM_USERS 60000
#define NUM_ITEMS 40000
#define NUM_NODES 100000
#define DIM       64
#define NUM_EDGES 1200000
#define BATCH     16384

#define BROWS 128                 // rows per bucket
#define NBUCK 782                 // ceil(100000/128)
#define CAP   2048                // padded slots per bucket (mean 1535, +13 sigma)
#define EPB   16384               // edges per bin_edges block

// ---------------------------------------------------------------------------
// concat user_emb / item_emb into x (float4; boundary is f4-aligned)
// ---------------------------------------------------------------------------
__global__ __launch_bounds__(256) void concat_kernel(
    const float4* __restrict__ ue, const float4* __restrict__ ie,
    float4* __restrict__ x)
{
    const int nU4 = NUM_USERS * (DIM / 4);
    const int total4 = NUM_NODES * (DIM / 4);
    int i = blockIdx.x * blockDim.x + threadIdx.x;
    int stride = gridDim.x * blockDim.x;
    for (; i < total4; i += stride)
        x[i] = (i < nU4) ? ue[i] : ie[i - nU4];
}

// ---------------------------------------------------------------------------
// 0) init bucket cursors to padded bases: gcursor[b] = b*CAP
// ---------------------------------------------------------------------------
__global__ __launch_bounds__(256) void init_cursors(int* __restrict__ gcursor)
{
    int b = blockIdx.x * blockDim.x + threadIdx.x;
    if (b < NBUCK) gcursor[b] = b * CAP;
}

// ---------------------------------------------------------------------------
// 1) bin edges into 782 coarse buckets (padded regions). Two passes over the
//    block's 16384 edges (count, then write) -> no register staging, long
//    contiguous per-bucket runs. Packed u64: [val:32][lrow:7][col:17]
// ---------------------------------------------------------------------------
__global__ __launch_bounds__(256) void bin_edges(
    const int* __restrict__ rows, const int* __restrict__ cols,
    const float* __restrict__ vals, int* __restrict__ gcursor,
    unsigned long long* __restrict__ tmp)
{
    __shared__ int cnt[NBUCK], lcur[NBUCK], gbase[NBUCK];
    int t = threadIdx.x;
    for (int i = t; i < NBUCK; i += 256) { cnt[i] = 0; lcur[i] = 0; }
    __syncthreads();
    int base = blockIdx.x * EPB;
    int lim = NUM_EDGES - base; if (lim > EPB) lim = EPB;
    // pass 1: count
    for (int k = t; k < lim; k += 256)
        atomicAdd(&cnt[rows[base + k] >> 7], 1);
    __syncthreads();
    // reserve global runs
    for (int i = t; i < NBUCK; i += 256) {
        int c = cnt[i];
        gbase[i] = c ? atomicAdd(&gcursor[i], c) : 0;
    }
    __syncthreads();
    // pass 2: write
    for (int k = t; k < lim; k += 256) {
        int idx = base + k;
        int r = rows[idx];
        int b = r >> 7;
        int lofs = atomicAdd(&lcur[b], 1);
        unsigned long long packed =
            ((unsigned long long)(unsigned)__float_as_int(vals[idx]) << 32)
            | ((unsigned)(r & 127) << 17) | (unsigned)cols[idx];
        tmp[(size_t)gbase[b] + lofs] = packed;
    }
}

// ---------------------------------------------------------------------------
// 2) exclusive scan of bucket counts -> exact CSR bases (1 block, 1024 thr)
// ---------------------------------------------------------------------------
__global__ __launch_bounds__(1024) void bucket_scan(
    const int* __restrict__ gcursor, int* __restrict__ bbase, int* __restrict__ bcount)
{
    __shared__ int s[1024];
    int t = threadIdx.x;
    int c = (t < NBUCK) ? gcursor[t] - t * CAP : 0;
    s[t] = c;
    __syncthreads();
    #pragma unroll
    for (int off = 1; off < 1024; off <<= 1) {
        int x = (t >= off) ? s[t - off] : 0;
        __syncthreads();
        s[t] += x;
        __syncthreads();
    }
    if (t < NBUCK) {
        bbase[t]  = s[t] - c;   // exclusive
        bcount[t] = c;
    }
}

// ---------------------------------------------------------------------------
// 3) one block per bucket: LDS per-row count + scan -> rowstart/rowend,
//    LDS counting sort, coalesced CSR write-out.
// ---------------------------------------------------------------------------
__global__ __launch_bounds__(256) void sort_buckets(
    const unsigned long long* __restrict__ tmp,
    const int* __restrict__ bbase, const int* __restrict__ bcount,
    int* __restrict__ rowstart, int* __restrict__ rowend,
    int2* __restrict__ csr)
{
    __shared__ int lcnt[BROWS], rowcur[BROWS], sscan[BROWS];
    __shared__ int2 stage[CAP];
    int b = blockIdx.x;
    int t = threadIdx.x;
    int count = bcount[b];
    int base  = bbase[b];
    const unsigned long long* src = tmp + (size_t)b * CAP;
    if (t < BROWS) lcnt[t] = 0;
    __syncthreads();
    // per-row counts
    for (int i = t; i < count; i += 256)
        atomicAdd(&lcnt[(int)((src[i] >> 17) & 127)], 1);
    __syncthreads();
    // 128-wide inclusive scan (first 128 threads hold data; all hit barriers)
    int myc = (t < BROWS) ? lcnt[t] : 0;
    if (t < BROWS) sscan[t] = myc;
    __syncthreads();
    #pragma unroll
    for (int off = 1; off < BROWS; off <<= 1) {
        int x = (t < BROWS && t >= off) ? sscan[t - off] : 0;
        __syncthreads();
        if (t < BROWS) sscan[t] += x;
        __syncthreads();
    }
    if (t < BROWS) {
        int excl = sscan[t] - myc;
        rowcur[t] = excl;
        int row = b * BROWS + t;
        if (row < NUM_NODES) {
            rowstart[row] = base + excl;
            rowend[row]   = base + excl + myc;
        }
    }
    __syncthreads();
    // counting sort into stage
    for (int i = t; i < count; i += 256) {
        unsigned long long v = src[i];
        int lrow = (int)((v >> 17) & 127);
        int pos = atomicAdd(&rowcur[lrow], 1);
        stage[pos] = make_int2((int)(v & 0x1FFFF), (int)(v >> 32));
    }
    __syncthreads();
    // coalesced write-out
    for (int i = t; i < count; i += 256)
        csr[(size_t)base + i] = stage[i];
}

// ---------------------------------------------------------------------------
// 4) CSR SpMM: 16 lanes per row (4 rows/wave), float4 per lane, 4x unroll
// ---------------------------------------------------------------------------
__global__ __launch_bounds__(256) void spmm_csr(
    const int* __restrict__ rowstart, const int* __restrict__ rowend,
    const int2* __restrict__ csr,
    const float* __restrict__ x, float* __restrict__ y)
{
    int tid = blockIdx.x * blockDim.x + threadIdx.x;
    int row = tid >> 4;
    if (row >= NUM_NODES) return;
    int q = tid & 15;
    int e   = rowstart[row];
    int end = rowend[row];
    const float4* xb = (const float4*)x;
    float4 acc = make_float4(0.f, 0.f, 0.f, 0.f);
    for (; e + 3 < end; e += 4) {
        int2 p0 = csr[e], p1 = csr[e + 1], p2 = csr[e + 2], p3 = csr[e + 3];
        float4 x0 = xb[((size_t)p0.x << 4) + q];
        float4 x1 = xb[((size_t)p1.x << 4) + q];
        float4 x2 = xb[((size_t)p2.x << 4) + q];
        float4 x3 = xb[((size_t)p3.x << 4) + q];
        float v0 = __int_as_float(p0.y), v1 = __int_as_float(p1.y);
        float v2 = __int_as_float(p2.y), v3 = __int_as_float(p3.y);
        acc.x = fmaf(v0, x0.x, acc.x); acc.y = fmaf(v0, x0.y, acc.y);
        acc.z = fmaf(v0, x0.z, acc.z); acc.w = fmaf(v0, x0.w, acc.w);
        acc.x = fmaf(v1, x1.x, acc.x); acc.y = fmaf(v1, x1.y, acc.y);
        acc.z = fmaf(v1, x1.z, acc.z); acc.w = fmaf(v1, x1.w, acc.w);
        acc.x = fmaf(v2, x2.x, acc.x); acc.y = fmaf(v2, x2.y, acc.y);
        acc.z = fmaf(v2, x2.z, acc.z); acc.w = fmaf(v2, x2.w, acc.w);
        acc.x = fmaf(v3, x3.x, acc.x); acc.y = fmaf(v3, x3.y, acc.y);
        acc.z = fmaf(v3, x3.z, acc.z); acc.w = fmaf(v3, x3.w, acc.w);
    }
    for (; e < end; ++e) {
        int2 p0 = csr[e];
        float4 x0 = xb[((size_t)p0.x << 4) + q];
        float v0 = __int_as_float(p0.y);
        acc.x = fmaf(v0, x0.x, acc.x); acc.y = fmaf(v0, x0.y, acc.y);
        acc.z = fmaf(v0, x0.z, acc.z); acc.w = fmaf(v0, x0.w, acc.w);
    }
    ((float4*)y)[((size_t)row << 4) + q] = acc;
}

// ---------------------------------------------------------------------------
// 5) batched dot: one wave per batch element
// ---------------------------------------------------------------------------
__global__ __launch_bounds__(256) void dot_kernel(
    const int*   __restrict__ uidx,
    const int*   __restrict__ iidx,
    const float* __restrict__ x,
    float*       __restrict__ out)
{
    int wid  = (blockIdx.x * blockDim.x + threadIdx.x) >> 6;
    int lane = threadIdx.x & 63;
    if (wid >= BATCH) return;
    int u  = uidx[wid];
    int it = iidx[wid];
    float a = x[(size_t)u * DIM + lane];
    float b = x[((size_t)NUM_USERS + it) * DIM + lane];
    float p = a * b;
    #pragma unroll
    for (int off = 32; off > 0; off >>= 1)
        p += __shfl_down(p, off);
    if (lane == 0) out[wid] = p;
}

extern "C" void kernel_launch(void* const* d_in, const int* in_sizes, int n_in,
                              void* d_out, int out_size, void* d_ws, size_t ws_size,
                              hipStream_t stream)
{
    const int*   user_indices = (const int*)  d_in[0];
    const int*   item_indices = (const int*)  d_in[1];
    const int*   edge_rows    = (const int*)  d_in[2];
    const int*   edge_cols    = (const int*)  d_in[3];
    const float* edge_vals    = (const float*)d_in[4];
    const float* user_emb     = (const float*)d_in[5];
    const float* item_emb     = (const float*)d_in[6];
    float*       out          = (float*)      d_out;

    // ---- workspace layout ----
    const size_t nfloats = (size_t)NUM_NODES * DIM;   // 6.4M floats
    char* p = (char*)d_ws;
    float* bufA     = (float*)p;  p += nfloats * 4;             // 25.6 MB (tmp alias)
    float* bufB     = (float*)p;  p += nfloats * 4;             // 25.6 MB
    int*   rowstart = (int*)p;    p += 102400 * 4;
    int*   rowend   = (int*)p;    p += 102400 * 4;
    int*   gcursor  = (int*)p;    p += 1024 * 4;
    int*   bbase    = (int*)p;    p += 1024 * 4;
    int*   bcount   = (int*)p;    p += 1024 * 4;
    int2*  csr      = (int2*)p;   p += (size_t)NUM_EDGES * 8;   // 9.6 MB

    // tmp (padded buckets): NBUCK*CAP*8 = 12.8 MB, aliases bufA (dead until concat)
    unsigned long long* tmp = (unsigned long long*)bufA;

    const int NB_BIN = (NUM_EDGES + EPB - 1) / EPB;   // 74

    // ---- build CSR (no global histogram, no global scan chain) ----
    init_cursors<<<(NBUCK + 255) / 256, 256, 0, stream>>>(gcursor);
    bin_edges<<<NB_BIN, 256, 0, stream>>>(edge_rows, edge_cols, edge_vals, gcursor, tmp);
    bucket_scan<<<1, 1024, 0, stream>>>(gcursor, bbase, bcount);
    sort_buckets<<<NBUCK, 256, 0, stream>>>(tmp, bbase, bcount, rowstart, rowend, csr);

    // ---- concat embeddings (tmp is dead now) ----
    concat_kernel<<<2048, 256, 0, stream>>>(
        (const float4*)user_emb, (const float4*)item_emb, (float4*)bufA);

    // ---- 3 SpMM layers ----
    const int NB_SPMM = (NUM_NODES * 16 + 255) / 256;   // 6250
    spmm_csr<<<NB_SPMM, 256, 0, stream>>>(rowstart, rowend, csr, bufA, bufB);
    spmm_csr<<<NB_SPMM, 256, 0, stream>>>(rowstart, rowend, csr, bufB, bufA);
    spmm_csr<<<NB_SPMM, 256, 0, stream>>>(rowstart, rowend, csr, bufA, bufB);

    // ---- final dot ----
    dot_kernel<<<(BATCH * 64) / 256, 256, 0, stream>>>(
        user_indices, item_indices, bufB, out);
}

// Round 6
// 192.084 us; speedup vs baseline: 4.2710x; 1.1474x over previous
//
#include <hip/hip_runtime.h>

#define NUM_USERS 60000
#define NUM_ITEMS 40000
#define NUM_NODES 100000
#define DIM       64
#define NUM_EDGES 1200000
#define BATCH     16384

#define BROWS 128                 // rows per bucket
#define NBUCK 782                 // ceil(100000/128)
#define CAP   2048                // padded slots per bucket (mean 1535, +13 sigma)
#define EPB   4096                // edges per bin_edges block -> 293 blocks

// ---------------------------------------------------------------------------
// concat user_emb / item_emb into x (float4; boundary is f4-aligned)
// ---------------------------------------------------------------------------
__global__ __launch_bounds__(256) void concat_kernel(
    const float4* __restrict__ ue, const float4* __restrict__ ie,
    float4* __restrict__ x)
{
    const int nU4 = NUM_USERS * (DIM / 4);
    const int total4 = NUM_NODES * (DIM / 4);
    int i = blockIdx.x * blockDim.x + threadIdx.x;
    int stride = gridDim.x * blockDim.x;
    for (; i < total4; i += stride)
        x[i] = (i < nU4) ? ue[i] : ie[i - nU4];
}

// ---------------------------------------------------------------------------
// 0) init bucket cursors to padded bases: gcursor[b] = b*CAP
// ---------------------------------------------------------------------------
__global__ __launch_bounds__(256) void init_cursors(int* __restrict__ gcursor)
{
    int b = blockIdx.x * blockDim.x + threadIdx.x;
    if (b < NBUCK) gcursor[b] = b * CAP;
}

// ---------------------------------------------------------------------------
// 1) bin edges into 782 coarse buckets (padded regions). Two passes over the
//    block's 4096 edges (count, then write). Packed u64: [val:32][lrow:7][col:17]
// ---------------------------------------------------------------------------
__global__ __launch_bounds__(256) void bin_edges(
    const int* __restrict__ rows, const int* __restrict__ cols,
    const float* __restrict__ vals, int* __restrict__ gcursor,
    unsigned long long* __restrict__ tmp)
{
    __shared__ int cnt[NBUCK], lcur[NBUCK], gbase[NBUCK];
    int t = threadIdx.x;
    for (int i = t; i < NBUCK; i += 256) { cnt[i] = 0; lcur[i] = 0; }
    __syncthreads();
    int base = blockIdx.x * EPB;
    int lim = NUM_EDGES - base; if (lim > EPB) lim = EPB;
    // pass 1: count
    for (int k = t; k < lim; k += 256)
        atomicAdd(&cnt[rows[base + k] >> 7], 1);
    __syncthreads();
    // reserve global runs
    for (int i = t; i < NBUCK; i += 256) {
        int c = cnt[i];
        gbase[i] = c ? atomicAdd(&gcursor[i], c) : 0;
    }
    __syncthreads();
    // pass 2: write
    for (int k = t; k < lim; k += 256) {
        int idx = base + k;
        int r = rows[idx];
        int b = r >> 7;
        int lofs = atomicAdd(&lcur[b], 1);
        unsigned long long packed =
            ((unsigned long long)(unsigned)__float_as_int(vals[idx]) << 32)
            | ((unsigned)(r & 127) << 17) | (unsigned)cols[idx];
        tmp[(size_t)gbase[b] + lofs] = packed;
    }
}

// ---------------------------------------------------------------------------
// 2) exclusive scan of bucket counts -> exact CSR bases (1 block, 1024 thr)
// ---------------------------------------------------------------------------
__global__ __launch_bounds__(1024) void bucket_scan(
    const int* __restrict__ gcursor, int* __restrict__ bbase, int* __restrict__ bcount)
{
    __shared__ int s[1024];
    int t = threadIdx.x;
    int c = (t < NBUCK) ? gcursor[t] - t * CAP : 0;
    s[t] = c;
    __syncthreads();
    #pragma unroll
    for (int off = 1; off < 1024; off <<= 1) {
        int x = (t >= off) ? s[t - off] : 0;
        __syncthreads();
        s[t] += x;
        __syncthreads();
    }
    if (t < NBUCK) {
        bbase[t]  = s[t] - c;   // exclusive
        bcount[t] = c;
    }
}

// ---------------------------------------------------------------------------
// 3) one block per bucket: LDS per-row count + scan -> rse (start,end),
//    LDS counting sort, coalesced CSR write-out.
// ---------------------------------------------------------------------------
__global__ __launch_bounds__(256) void sort_buckets(
    const unsigned long long* __restrict__ tmp,
    const int* __restrict__ bbase, const int* __restrict__ bcount,
    int2* __restrict__ rse, int2* __restrict__ csr)
{
    __shared__ int lcnt[BROWS], rowcur[BROWS], sscan[BROWS];
    __shared__ int2 stage[CAP];
    int b = blockIdx.x;
    int t = threadIdx.x;
    int count = bcount[b];
    int base  = bbase[b];
    const unsigned long long* src = tmp + (size_t)b * CAP;
    if (t < BROWS) lcnt[t] = 0;
    __syncthreads();
    // per-row counts
    for (int i = t; i < count; i += 256)
        atomicAdd(&lcnt[(int)((src[i] >> 17) & 127)], 1);
    __syncthreads();
    // 128-wide inclusive scan
    int myc = (t < BROWS) ? lcnt[t] : 0;
    if (t < BROWS) sscan[t] = myc;
    __syncthreads();
    #pragma unroll
    for (int off = 1; off < BROWS; off <<= 1) {
        int x = (t < BROWS && t >= off) ? sscan[t - off] : 0;
        __syncthreads();
        if (t < BROWS) sscan[t] += x;
        __syncthreads();
    }
    if (t < BROWS) {
        int excl = sscan[t] - myc;
        rowcur[t] = excl;
        int row = b * BROWS + t;
        if (row < NUM_NODES)
            rse[row] = make_int2(base + excl, base + excl + myc);
    }
    __syncthreads();
    // counting sort into stage
    for (int i = t; i < count; i += 256) {
        unsigned long long v = src[i];
        int lrow = (int)((v >> 17) & 127);
        int pos = atomicAdd(&rowcur[lrow], 1);
        stage[pos] = make_int2((int)(v & 0x1FFFF), (int)(v >> 32));
    }
    __syncthreads();
    // coalesced write-out
    for (int i = t; i < count; i += 256)
        csr[(size_t)base + i] = stage[i];
}

// ---------------------------------------------------------------------------
// 4) CSR SpMM: 16 lanes per row (4 rows/wave), float4 per lane, 4x unroll
// ---------------------------------------------------------------------------
__global__ __launch_bounds__(256) void spmm_csr(
    const int2* __restrict__ rse, const int2* __restrict__ csr,
    const float* __restrict__ x, float* __restrict__ y)
{
    int tid = blockIdx.x * blockDim.x + threadIdx.x;
    int row = tid >> 4;
    if (row >= NUM_NODES) return;
    int q = tid & 15;
    int2 se = rse[row];
    int e   = se.x;
    int end = se.y;
    const float4* xb = (const float4*)x;
    float4 acc = make_float4(0.f, 0.f, 0.f, 0.f);
    for (; e + 3 < end; e += 4) {
        int2 p0 = csr[e], p1 = csr[e + 1], p2 = csr[e + 2], p3 = csr[e + 3];
        float4 x0 = xb[((size_t)p0.x << 4) + q];
        float4 x1 = xb[((size_t)p1.x << 4) + q];
        float4 x2 = xb[((size_t)p2.x << 4) + q];
        float4 x3 = xb[((size_t)p3.x << 4) + q];
        float v0 = __int_as_float(p0.y), v1 = __int_as_float(p1.y);
        float v2 = __int_as_float(p2.y), v3 = __int_as_float(p3.y);
        acc.x = fmaf(v0, x0.x, acc.x); acc.y = fmaf(v0, x0.y, acc.y);
        acc.z = fmaf(v0, x0.z, acc.z); acc.w = fmaf(v0, x0.w, acc.w);
        acc.x = fmaf(v1, x1.x, acc.x); acc.y = fmaf(v1, x1.y, acc.y);
        acc.z = fmaf(v1, x1.z, acc.z); acc.w = fmaf(v1, x1.w, acc.w);
        acc.x = fmaf(v2, x2.x, acc.x); acc.y = fmaf(v2, x2.y, acc.y);
        acc.z = fmaf(v2, x2.z, acc.z); acc.w = fmaf(v2, x2.w, acc.w);
        acc.x = fmaf(v3, x3.x, acc.x); acc.y = fmaf(v3, x3.y, acc.y);
        acc.z = fmaf(v3, x3.z, acc.z); acc.w = fmaf(v3, x3.w, acc.w);
    }
    for (; e < end; ++e) {
        int2 p0 = csr[e];
        float4 x0 = xb[((size_t)p0.x << 4) + q];
        float v0 = __int_as_float(p0.y);
        acc.x = fmaf(v0, x0.x, acc.x); acc.y = fmaf(v0, x0.y, acc.y);
        acc.z = fmaf(v0, x0.z, acc.z); acc.w = fmaf(v0, x0.w, acc.w);
    }
    ((float4*)y)[((size_t)row << 4) + q] = acc;
}

// ---------------------------------------------------------------------------
// 5) batched dot: one wave per batch element
// ---------------------------------------------------------------------------
__global__ __launch_bounds__(256) void dot_kernel(
    const int*   __restrict__ uidx,
    const int*   __restrict__ iidx,
    const float* __restrict__ x,
    float*       __restrict__ out)
{
    int wid  = (blockIdx.x * blockDim.x + threadIdx.x) >> 6;
    int lane = threadIdx.x & 63;
    if (wid >= BATCH) return;
    int u  = uidx[wid];
    int it = iidx[wid];
    float a = x[(size_t)u * DIM + lane];
    float b = x[((size_t)NUM_USERS + it) * DIM + lane];
    float p = a * b;
    #pragma unroll
    for (int off = 32; off > 0; off >>= 1)
        p += __shfl_down(p, off);
    if (lane == 0) out[wid] = p;
}

extern "C" void kernel_launch(void* const* d_in, const int* in_sizes, int n_in,
                              void* d_out, int out_size, void* d_ws, size_t ws_size,
                              hipStream_t stream)
{
    const int*   user_indices = (const int*)  d_in[0];
    const int*   item_indices = (const int*)  d_in[1];
    const int*   edge_rows    = (const int*)  d_in[2];
    const int*   edge_cols    = (const int*)  d_in[3];
    const float* edge_vals    = (const float*)d_in[4];
    const float* user_emb     = (const float*)d_in[5];
    const float* item_emb     = (const float*)d_in[6];
    float*       out          = (float*)      d_out;

    // ---- workspace layout ----
    const size_t nfloats = (size_t)NUM_NODES * DIM;   // 6.4M floats
    char* p = (char*)d_ws;
    float* bufA     = (float*)p;  p += nfloats * 4;             // 25.6 MB (tmp alias)
    float* bufB     = (float*)p;  p += nfloats * 4;             // 25.6 MB
    int2*  rse      = (int2*)p;   p += 102400 * 8;
    int*   gcursor  = (int*)p;    p += 1024 * 4;
    int*   bbase    = (int*)p;    p += 1024 * 4;
    int*   bcount   = (int*)p;    p += 1024 * 4;
    int2*  csr      = (int2*)p;   p += (size_t)NUM_EDGES * 8;   // 9.6 MB

    // tmp (padded buckets): NBUCK*CAP*8 = 12.8 MB, aliases bufA (dead before concat)
    unsigned long long* tmp = (unsigned long long*)bufA;

    const int NB_BIN = (NUM_EDGES + EPB - 1) / EPB;   // 293

    // ---- build CSR ----
    init_cursors<<<(NBUCK + 255) / 256, 256, 0, stream>>>(gcursor);
    bin_edges<<<NB_BIN, 256, 0, stream>>>(edge_rows, edge_cols, edge_vals, gcursor, tmp);
    bucket_scan<<<1, 1024, 0, stream>>>(gcursor, bbase, bcount);
    sort_buckets<<<NBUCK, 256, 0, stream>>>(tmp, bbase, bcount, rse, csr);

    // ---- concat embeddings (tmp is dead now) ----
    concat_kernel<<<2048, 256, 0, stream>>>(
        (const float4*)user_emb, (const float4*)item_emb, (float4*)bufA);

    // ---- 3 SpMM layers ----
    const int NB_SPMM = (NUM_NODES * 16 + 255) / 256;   // 6250
    spmm_csr<<<NB_SPMM, 256, 0, stream>>>(rse, csr, bufA, bufB);
    spmm_csr<<<NB_SPMM, 256, 0, stream>>>(rse, csr, bufB, bufA);
    spmm_csr<<<NB_SPMM, 256, 0, stream>>>(rse, csr, bufA, bufB);

    // ---- final dot ----
    dot_kernel<<<(BATCH * 64) / 256, 256, 0, stream>>>(
        user_indices, item_indices, bufB, out);
}

// Round 7
// 187.885 us; speedup vs baseline: 4.3664x; 1.0223x over previous
//
#include <hip/hip_runtime.h>

#define NUM_USERS 60000
#define NUM_ITEMS 40000
#define NUM_NODES 100000
#define DIM       64
#define NUM_EDGES 1200000
#define BATCH     16384

#define BROWS 128                 // rows per bucket
#define NBUCK 782                 // ceil(100000/128)
#define CAP   2048                // padded slots per bucket
#define EPB   4096                // edges per bin_edges block -> 293 blocks
#define NFLAGW 3125               // 100000 bits in u32 words

// ---------------------------------------------------------------------------
// 0) init bucket cursors to padded bases
// ---------------------------------------------------------------------------
__global__ __launch_bounds__(256) void init_cursors(int* __restrict__ gcursor)
{
    int b = blockIdx.x * blockDim.x + threadIdx.x;
    if (b < NBUCK) gcursor[b] = b * CAP;
}

// ---------------------------------------------------------------------------
// 1) bin edges into 782 coarse buckets (padded regions).
//    Packed u64: [val:32][lrow:7][col:17]
// ---------------------------------------------------------------------------
__global__ __launch_bounds__(256) void bin_edges(
    const int* __restrict__ rows, const int* __restrict__ cols,
    const float* __restrict__ vals, int* __restrict__ gcursor,
    unsigned long long* __restrict__ tmp)
{
    __shared__ int cnt[NBUCK], lcur[NBUCK], gbase[NBUCK];
    int t = threadIdx.x;
    for (int i = t; i < NBUCK; i += 256) { cnt[i] = 0; lcur[i] = 0; }
    __syncthreads();
    int base = blockIdx.x * EPB;
    int lim = NUM_EDGES - base; if (lim > EPB) lim = EPB;
    for (int k = t; k < lim; k += 256)
        atomicAdd(&cnt[rows[base + k] >> 7], 1);
    __syncthreads();
    for (int i = t; i < NBUCK; i += 256) {
        int c = cnt[i];
        gbase[i] = c ? atomicAdd(&gcursor[i], c) : 0;
    }
    __syncthreads();
    for (int k = t; k < lim; k += 256) {
        int idx = base + k;
        int r = rows[idx];
        int b = r >> 7;
        int lofs = atomicAdd(&lcur[b], 1);
        unsigned long long packed =
            ((unsigned long long)(unsigned)__float_as_int(vals[idx]) << 32)
            | ((unsigned)(r & 127) << 17) | (unsigned)cols[idx];
        tmp[(size_t)gbase[b] + lofs] = packed;
    }
}

// ---------------------------------------------------------------------------
// 2) exclusive scan of bucket counts -> exact CSR bases
// ---------------------------------------------------------------------------
__global__ __launch_bounds__(1024) void bucket_scan(
    const int* __restrict__ gcursor, int* __restrict__ bbase, int* __restrict__ bcount)
{
    __shared__ int s[1024];
    int t = threadIdx.x;
    int c = (t < NBUCK) ? gcursor[t] - t * CAP : 0;
    s[t] = c;
    __syncthreads();
    #pragma unroll
    for (int off = 1; off < 1024; off <<= 1) {
        int x = (t >= off) ? s[t - off] : 0;
        __syncthreads();
        s[t] += x;
        __syncthreads();
    }
    if (t < NBUCK) {
        bbase[t]  = s[t] - c;
        bcount[t] = c;
    }
}

// ---------------------------------------------------------------------------
// 3) per-bucket LDS counting sort -> rse (start,end) + dense CSR
// ---------------------------------------------------------------------------
__global__ __launch_bounds__(256) void sort_buckets(
    const unsigned long long* __restrict__ tmp,
    const int* __restrict__ bbase, const int* __restrict__ bcount,
    int2* __restrict__ rse, int2* __restrict__ csr)
{
    __shared__ int lcnt[BROWS], rowcur[BROWS], sscan[BROWS];
    __shared__ int2 stage[CAP];
    int b = blockIdx.x;
    int t = threadIdx.x;
    int count = bcount[b];
    int base  = bbase[b];
    const unsigned long long* src = tmp + (size_t)b * CAP;
    if (t < BROWS) lcnt[t] = 0;
    __syncthreads();
    for (int i = t; i < count; i += 256)
        atomicAdd(&lcnt[(int)((src[i] >> 17) & 127)], 1);
    __syncthreads();
    int myc = (t < BROWS) ? lcnt[t] : 0;
    if (t < BROWS) sscan[t] = myc;
    __syncthreads();
    #pragma unroll
    for (int off = 1; off < BROWS; off <<= 1) {
        int x = (t < BROWS && t >= off) ? sscan[t - off] : 0;
        __syncthreads();
        if (t < BROWS) sscan[t] += x;
        __syncthreads();
    }
    if (t < BROWS) {
        int excl = sscan[t] - myc;
        rowcur[t] = excl;
        int row = b * BROWS + t;
        if (row < NUM_NODES)
            rse[row] = make_int2(base + excl, base + excl + myc);
    }
    __syncthreads();
    for (int i = t; i < count; i += 256) {
        unsigned long long v = src[i];
        int lrow = (int)((v >> 17) & 127);
        int pos = atomicAdd(&rowcur[lrow], 1);
        stage[pos] = make_int2((int)(v & 0x1FFFF), (int)(v >> 32));
    }
    __syncthreads();
    for (int i = t; i < count; i += 256)
        csr[(size_t)base + i] = stage[i];
}

// ---------------------------------------------------------------------------
// needed-row machinery for layer 3
// ---------------------------------------------------------------------------
__global__ __launch_bounds__(256) void flag_batch(
    const int* __restrict__ uidx, const int* __restrict__ iidx,
    unsigned* __restrict__ flags)
{
    int i = blockIdx.x * blockDim.x + threadIdx.x;
    if (i < BATCH) {
        int n = uidx[i];
        atomicOr(&flags[n >> 5], 1u << (n & 31));
    } else if (i < 2 * BATCH) {
        int n = NUM_USERS + iidx[i - BATCH];
        atomicOr(&flags[n >> 5], 1u << (n & 31));
    }
}

__global__ __launch_bounds__(256) void compact_rows(
    const unsigned* __restrict__ flags, int* __restrict__ list,
    int* __restrict__ nrows)
{
    int i = blockIdx.x * blockDim.x + threadIdx.x;
    if (i < NUM_NODES && ((flags[i >> 5] >> (i & 31)) & 1u)) {
        int pos = atomicAdd(nrows, 1);   // compiler wave-aggregates
        list[pos] = i;
    }
}

// ---------------------------------------------------------------------------
// SpMM row body: 16 lanes per row, float4 per lane, 8/4/1 pipelined gathers.
// xu/xi are the user/item base pointers (same buffer for inner layers).
// ---------------------------------------------------------------------------
__device__ __forceinline__ const float4* src_base(
    int c, const float4* __restrict__ xu, const float4* __restrict__ xi)
{
    return (c < NUM_USERS) ? xu + ((size_t)c << 4)
                           : xi + ((size_t)(c - NUM_USERS) << 4);
}

__device__ __forceinline__ void spmm_row(
    int row, int q, const int2* __restrict__ rse, const int2* __restrict__ csr,
    const float4* __restrict__ xu, const float4* __restrict__ xi,
    float* __restrict__ y)
{
    int2 se = rse[row];
    int e   = se.x;
    int end = se.y;
    float4 acc = make_float4(0.f, 0.f, 0.f, 0.f);
    for (; e + 7 < end; e += 8) {
        int2 pp[8];
        #pragma unroll
        for (int j = 0; j < 8; ++j) pp[j] = csr[e + j];
        float4 xv[8];
        #pragma unroll
        for (int j = 0; j < 8; ++j) xv[j] = src_base(pp[j].x, xu, xi)[q];
        #pragma unroll
        for (int j = 0; j < 8; ++j) {
            float v = __int_as_float(pp[j].y);
            acc.x = fmaf(v, xv[j].x, acc.x);
            acc.y = fmaf(v, xv[j].y, acc.y);
            acc.z = fmaf(v, xv[j].z, acc.z);
            acc.w = fmaf(v, xv[j].w, acc.w);
        }
    }
    for (; e + 3 < end; e += 4) {
        int2 pp[4];
        #pragma unroll
        for (int j = 0; j < 4; ++j) pp[j] = csr[e + j];
        float4 xv[4];
        #pragma unroll
        for (int j = 0; j < 4; ++j) xv[j] = src_base(pp[j].x, xu, xi)[q];
        #pragma unroll
        for (int j = 0; j < 4; ++j) {
            float v = __int_as_float(pp[j].y);
            acc.x = fmaf(v, xv[j].x, acc.x);
            acc.y = fmaf(v, xv[j].y, acc.y);
            acc.z = fmaf(v, xv[j].z, acc.z);
            acc.w = fmaf(v, xv[j].w, acc.w);
        }
    }
    for (; e < end; ++e) {
        int2 p0 = csr[e];
        float4 x0 = src_base(p0.x, xu, xi)[q];
        float v = __int_as_float(p0.y);
        acc.x = fmaf(v, x0.x, acc.x);
        acc.y = fmaf(v, x0.y, acc.y);
        acc.z = fmaf(v, x0.z, acc.z);
        acc.w = fmaf(v, x0.w, acc.w);
    }
    ((float4*)y)[((size_t)row << 4) + q] = acc;
}

// dense-row SpMM (layers 1 & 2)
__global__ __launch_bounds__(256) void spmm_csr(
    const int2* __restrict__ rse, const int2* __restrict__ csr,
    const float* __restrict__ xu, const float* __restrict__ xi,
    float* __restrict__ y)
{
    int tid = blockIdx.x * blockDim.x + threadIdx.x;
    int row = tid >> 4;
    if (row >= NUM_NODES) return;
    spmm_row(row, tid & 15, rse, csr, (const float4*)xu, (const float4*)xi, y);
}

// listed-row SpMM (layer 3: only rows the dot reads)
__global__ __launch_bounds__(256) void spmm_csr_list(
    const int* __restrict__ list, const int* __restrict__ nrows,
    const int2* __restrict__ rse, const int2* __restrict__ csr,
    const float* __restrict__ x, float* __restrict__ y)
{
    int tid = blockIdx.x * blockDim.x + threadIdx.x;
    int i = tid >> 4;
    if (i >= *nrows) return;
    const float4* xb = (const float4*)x;
    spmm_row(list[i], tid & 15, rse, csr, xb, xb + ((size_t)NUM_USERS << 4), y);
}

// ---------------------------------------------------------------------------
// batched dot: one wave per batch element
// ---------------------------------------------------------------------------
__global__ __launch_bounds__(256) void dot_kernel(
    const int*   __restrict__ uidx,
    const int*   __restrict__ iidx,
    const float* __restrict__ x,
    float*       __restrict__ out)
{
    int wid  = (blockIdx.x * blockDim.x + threadIdx.x) >> 6;
    int lane = threadIdx.x & 63;
    if (wid >= BATCH) return;
    int u  = uidx[wid];
    int it = iidx[wid];
    float a = x[(size_t)u * DIM + lane];
    float b = x[((size_t)NUM_USERS + it) * DIM + lane];
    float p = a * b;
    #pragma unroll
    for (int off = 32; off > 0; off >>= 1)
        p += __shfl_down(p, off);
    if (lane == 0) out[wid] = p;
}

extern "C" void kernel_launch(void* const* d_in, const int* in_sizes, int n_in,
                              void* d_out, int out_size, void* d_ws, size_t ws_size,
                              hipStream_t stream)
{
    const int*   user_indices = (const int*)  d_in[0];
    const int*   item_indices = (const int*)  d_in[1];
    const int*   edge_rows    = (const int*)  d_in[2];
    const int*   edge_cols    = (const int*)  d_in[3];
    const float* edge_vals    = (const float*)d_in[4];
    const float* user_emb     = (const float*)d_in[5];
    const float* item_emb     = (const float*)d_in[6];
    float*       out          = (float*)      d_out;

    // ---- workspace layout ----
    const size_t nfloats = (size_t)NUM_NODES * DIM;   // 6.4M floats
    char* p = (char*)d_ws;
    float*    bufA    = (float*)p;    p += nfloats * 4;             // 25.6 MB (tmp alias)
    float*    bufB    = (float*)p;    p += nfloats * 4;             // 25.6 MB
    int2*     rse     = (int2*)p;     p += 102400 * 8;
    int*      gcursor = (int*)p;      p += 1024 * 4;
    int*      bbase   = (int*)p;      p += 1024 * 4;
    int*      bcount  = (int*)p;      p += 1024 * 4;
    int*      nrows   = (int*)p;      p += 256 * 4;                 // cursor (+pad)
    unsigned* flags   = (unsigned*)p; p += 3328 * 4;                // 100K bits (+pad)
    int*      rowlist = (int*)p;      p += 33024 * 4;               // <= 32768 rows
    int2*     csr     = (int2*)p;     p += (size_t)NUM_EDGES * 8;   // 9.6 MB

    // tmp (padded buckets): NBUCK*CAP*8 = 12.8 MB, aliases bufA
    unsigned long long* tmp = (unsigned long long*)bufA;

    const int NB_BIN = (NUM_EDGES + EPB - 1) / EPB;   // 293

    // ---- build CSR ----
    init_cursors<<<(NBUCK + 255) / 256, 256, 0, stream>>>(gcursor);
    bin_edges<<<NB_BIN, 256, 0, stream>>>(edge_rows, edge_cols, edge_vals, gcursor, tmp);
    bucket_scan<<<1, 1024, 0, stream>>>(gcursor, bbase, bcount);
    sort_buckets<<<NBUCK, 256, 0, stream>>>(tmp, bbase, bcount, rse, csr);

    // ---- needed-rows list for layer 3 (cursor + flags cleared each call) ----
    hipMemsetAsync(nrows, 0, (256 + NFLAGW) * sizeof(int), stream);
    flag_batch<<<(2 * BATCH + 255) / 256, 256, 0, stream>>>(
        user_indices, item_indices, flags);
    compact_rows<<<(NUM_NODES + 255) / 256, 256, 0, stream>>>(
        flags, rowlist, nrows);

    // ---- 3 SpMM layers (layer 1 fuses the concat; layer 3 listed rows) ----
    const int NB_SPMM = (NUM_NODES * 16 + 255) / 256;   // 6250
    spmm_csr<<<NB_SPMM, 256, 0, stream>>>(rse, csr, user_emb, item_emb, bufB);
    spmm_csr<<<NB_SPMM, 256, 0, stream>>>(rse, csr, bufB, bufB + (size_t)NUM_USERS * DIM, bufA);
    spmm_csr_list<<<(32768 * 16) / 256, 256, 0, stream>>>(
        rowlist, nrows, rse, csr, bufA, bufB);

    // ---- final dot ----
    dot_kernel<<<(BATCH * 64) / 256, 256, 0, stream>>>(
        user_indices, item_indices, bufB, out);
}